// Round 7
// baseline (2707.262 us; speedup 1.0000x reference)
//
#include <hip/hip_runtime.h>

typedef unsigned int u32;
typedef unsigned short u16;

#define D 128

typedef __attribute__((ext_vector_type(8))) short bf16x8;
typedef __attribute__((ext_vector_type(4))) float f32x4;
#define MFMA16x16(a, b, c) __builtin_amdgcn_mfma_f32_16x16x32_bf16(a, b, c, 0, 0, 0)

__device__ inline float b2f(u32 h) { return __uint_as_float((h & 0xffffu) << 16); }
__device__ inline u16 f2b(float f) {
    u32 u = __float_as_uint(f);
    return (u16)((u + 0x7fffu + ((u >> 16) & 1u)) >> 16);
}
__device__ inline float tanh_fast(float x) {
    x = fminf(fmaxf(x, -15.f), 15.f);
    float e = __expf(2.f * x);
    return (e - 1.f) * __builtin_amdgcn_rcpf(e + 1.f);
}

// ---------------- zero int array ----------------
__global__ void k_zero(int* p, int n) {
    int i = blockIdx.x * 256 + threadIdx.x;
    if (i < n) p[i] = 0;
}

// ---- bucket histogram: keys = (node>>6)*8 + grp, grp = (chunk)&7 ----
// cnt layout: [attn keys: B64*8][mean keys: B64*8]
__global__ void k_hist_b(const int* __restrict__ er_src, const int* __restrict__ er_dst,
                         const int* __restrict__ ee_src, const int* __restrict__ rr_src,
                         int* __restrict__ cnt, int E_ER, int E_EE, int E_RR, int B64) {
    extern __shared__ int bins[];  // 2*B64
    int nb = 2 * B64;
    for (int i = threadIdx.x; i < nb; i += 256) bins[i] = 0;
    __syncthreads();
    int E_T = 2 * E_ER + E_EE + E_RR;
    int C = (E_T + 255) >> 8;
    int b = blockIdx.x, G = gridDim.x, grp = b & 7;
    for (int c = grp + 8 * (b >> 3); c < C; c += G) {
        int i = c * 256 + threadIdx.x;
        if (i >= E_T) continue;
        if (i < E_ER) {
            atomicAdd(&bins[er_src[i] >> 6], 1);
        } else {
            int j = i - E_ER;
            int sct;
            if (j < E_ER) sct = er_dst[j];
            else {
                j -= E_ER;
                sct = (j < E_EE) ? ee_src[j] : rr_src[j - E_EE];
            }
            atomicAdd(&bins[B64 + (sct >> 6)], 1);
        }
    }
    __syncthreads();
    for (int i = threadIdx.x; i < nb; i += 256) {
        int v = bins[i];
        if (v) {
            int key = (i < B64) ? (i * 8 + grp) : (B64 * 8 + (i - B64) * 8 + grp);
            atomicAdd(&cnt[key], v);
        }
    }
}

// ---- one-block exclusive scan over K2 counters -> off (K2+1), cur (K2) ----
__global__ void k_scan_b(const int* __restrict__ cnt, int K2,
                         int* __restrict__ off, int* __restrict__ cur) {
    __shared__ int sh[256];
    int t = threadIdx.x;
    int per = (K2 + 255) / 256;
    int b0 = t * per, b1 = b0 + per;
    if (b1 > K2) b1 = K2;
    int sum = 0;
    for (int i = b0; i < b1; i++) sum += cnt[i];
    sh[t] = sum;
    __syncthreads();
    for (int o = 1; o < 256; o <<= 1) {
        int x = (t >= o) ? sh[t - o] : 0;
        __syncthreads();
        sh[t] += x;
        __syncthreads();
    }
    int pre = sh[t] - sum;
    for (int i = b0; i < b1; i++) {
        int c = cnt[i];
        off[i] = pre;
        cur[i] = pre;
        pre += c;
    }
    if (t == 255) off[K2] = pre;  // grand total = E_T
}

// ---- bucketed fill: ticket scatter, tails XCD-local via grp trick ----
// attn entry (4B): dst | (src&63)<<17 ; mean entry (8B): (gat | (sct&63)<<17, w)
__global__ void k_fill_b(const int* __restrict__ er_src, const int* __restrict__ er_dst,
                         const int* __restrict__ ee_src, const int* __restrict__ ee_dst,
                         const int* __restrict__ rr_src, const int* __restrict__ rr_dst,
                         const float* __restrict__ ee_w, int* __restrict__ cur,
                         u32* __restrict__ gpackA, uint2* __restrict__ gpackM,
                         int E_ER, int E_EE, int E_RR, int B64) {
    int E_T = 2 * E_ER + E_EE + E_RR;
    int C = (E_T + 255) >> 8;
    int b = blockIdx.x, G = gridDim.x, grp = b & 7;
    for (int c = grp + 8 * (b >> 3); c < C; c += G) {
        int i = c * 256 + threadIdx.x;
        if (i >= E_T) continue;
        if (i < E_ER) {
            int src = er_src[i], dst = er_dst[i];
            int p = atomicAdd(&cur[(src >> 6) * 8 + grp], 1);
            gpackA[p] = (u32)dst | ((u32)(src & 63) << 17);
        } else {
            int j = i - E_ER;
            int sct, gat;
            float w;
            if (j < E_ER) {
                sct = er_dst[j]; gat = er_src[j]; w = 1.f;
            } else {
                j -= E_ER;
                if (j < E_EE) { sct = ee_src[j]; gat = ee_dst[j]; w = ee_w[j]; }
                else { j -= E_EE; sct = rr_src[j]; gat = rr_dst[j]; w = 1.f; }
            }
            int p = atomicAdd(&cur[B64 * 8 + (sct >> 6) * 8 + grp], 1) - E_ER;
            gpackM[p] = make_uint2((u32)gat | ((u32)(sct & 63) << 17), __float_as_uint(w));
        }
    }
}

// ---------------- casts ----------------
__global__ void k_cast4(const float* __restrict__ src, u16* __restrict__ dst, int n4) {
    int i = blockIdx.x * 256 + threadIdx.x;
    if (i >= n4) return;
    float4 v = ((const float4*)src)[i];
    ushort4 o;
    o.x = f2b(v.x); o.y = f2b(v.y); o.z = f2b(v.z); o.w = f2b(v.w);
    ((ushort4*)dst)[i] = o;
}

__global__ void k_cast_w(const float* __restrict__ Wattn,
                         const float* __restrict__ W1, const float* __restrict__ W2,
                         const float* __restrict__ W3,
                         u16* __restrict__ Wcat, u16* __restrict__ W123h) {
    int i = blockIdx.x * 256 + threadIdx.x;
    if (i < 32768) {
        int dd = i >> 7, k = i & 127;
        float v = (dd < 128) ? Wattn[(size_t)dd * 256 + k]
                             : Wattn[(size_t)(dd - 128) * 256 + 128 + k];
        Wcat[i] = f2b(v);
        return;
    }
    i -= 32768;
    if (i < 16384) { W123h[i] = f2b(W1[i]); return; }
    i -= 16384;
    if (i < 16384) { W123h[16384 + i] = f2b(W2[i]); return; }
    i -= 16384;
    if (i < 16384) W123h[32768 + i] = f2b(W3[i]);
}

// --- A = embh @ Wcat^T via MFMA. A[n][dd] bf16, dd in [0,256) ---
__global__ __launch_bounds__(256) void k_precompute_mfma(const u16* __restrict__ embh,
                                                         const u16* __restrict__ Wcat,
                                                         u16* __restrict__ A, int N) {
    __shared__ u16 sX[64][136];
    int nb = blockIdx.x * 64;
    int tid = threadIdx.x;
    for (int i = tid; i < 1024; i += 256) {
        int row = i >> 4, c8 = i & 15;
        int n = nb + row;
        uint4 v = make_uint4(0u, 0u, 0u, 0u);
        if (n < N) v = *(const uint4*)(embh + (size_t)n * 128 + c8 * 8);
        *(uint4*)&sX[row][c8 * 8] = v;
    }
    __syncthreads();
    int wid = tid >> 6, lane = tid & 63;
    int quad = lane >> 4, l15 = lane & 15;
#pragma unroll
    for (int ns = 0; ns < 4; ns++) {
        int dbase = (wid * 4 + ns) * 16;
        bf16x8 b[4];
#pragma unroll
        for (int ks = 0; ks < 4; ks++)
            b[ks] = *(const bf16x8*)(Wcat + (size_t)(dbase + l15) * 128 + ks * 32 + quad * 8);
#pragma unroll
        for (int ms = 0; ms < 4; ms++) {
            f32x4 acc = {0.f, 0.f, 0.f, 0.f};
#pragma unroll
            for (int ks = 0; ks < 4; ks++) {
                bf16x8 a = *(const bf16x8*)&sX[ms * 16 + l15][ks * 32 + quad * 8];
                acc = MFMA16x16(a, b[ks], acc);
            }
#pragma unroll
            for (int r = 0; r < 4; r++) {
                int row = nb + ms * 16 + quad * 4 + r;
                if (row < N) A[(size_t)row * 256 + dbase + l15] = f2b(acc[r]);
            }
        }
    }
}

// ---- bucketed attention: LDS accumulators, max-free softmax (|v|<=11.4) ----
__global__ __launch_bounds__(256) void k_attn_b(const u16* __restrict__ A,
                                                const u32* __restrict__ gpackA,
                                                const int* __restrict__ off,
                                                const u16* __restrict__ embh,
                                                const float* __restrict__ Wb,
                                                const float* __restrict__ w0w,
                                                const float* __restrict__ w0b,
                                                u16* __restrict__ attn_h, int N) {
    __shared__ float acc[64 * 128];
    __shared__ float lsum[64];
    int tid = threadIdx.x;
    for (int i = tid; i < 64 * 128; i += 256) acc[i] = 0.f;
    if (tid < 64) lsum[tid] = 0.f;
    int bkt = blockIdx.x;
    int n0 = bkt * 64;
    int lane = tid & 63, wave = tid >> 6;
    float bx = Wb[lane], by = Wb[lane + 64];
    float wx = w0w[lane], wy = w0w[lane + 64];
    float w0bias = w0b[0];
    __syncthreads();
    int s0 = off[bkt * 8], s1 = off[(bkt + 1) * 8];
    for (int s = s0 + wave; s < s1; s += 4) {
        u32 e = gpackA[s];
        int dst = e & 0x1FFFF;
        int nl = (e >> 17) & 63;
        const u16* ah = A + (size_t)(n0 + nl) * 256 + 128;  // bucket-local: L1-hot
        const u16* ar = A + (size_t)dst * 256;
        float p = tanh_fast(b2f(ar[lane]) + b2f(ah[lane]) + bx) * wx +
                  tanh_fast(b2f(ar[lane + 64]) + b2f(ah[lane + 64]) + by) * wy;
#pragma unroll
        for (int o = 32; o; o >>= 1) p += __shfl_xor(p, o);
        float ev = __expf(p + w0bias);
        const u16* em = embh + (size_t)dst * 128;
        atomicAdd(&acc[nl * 128 + lane], ev * b2f(em[lane]));
        atomicAdd(&acc[nl * 128 + 64 + lane], ev * b2f(em[lane + 64]));
        if (lane == 0) atomicAdd(&lsum[nl], ev);
    }
    __syncthreads();
    for (int i = tid; i < 64 * 64; i += 256) {
        int nl = i >> 6, dp = i & 63;
        int node = n0 + nl;
        if (node < N) {
            float inv = 1.f / (lsum[nl] + 1e-9f);
            u32 o = (u32)f2b(acc[nl * 128 + 2 * dp] * inv) |
                    ((u32)f2b(acc[nl * 128 + 2 * dp + 1] * inv) << 16);
            *(u32*)(attn_h + (size_t)node * 128 + 2 * dp) = o;
        }
    }
}

// ---- bucketed mean aggregation: LDS accumulators ----
__global__ __launch_bounds__(256) void k_mean_b(const uint2* __restrict__ gpackM,
                                                const int* __restrict__ off,
                                                const u16* __restrict__ embh,
                                                u16* __restrict__ mean_h,
                                                int N, int B64, int E_ER) {
    __shared__ float acc[64 * 128];
    __shared__ float csum[64];
    int tid = threadIdx.x;
    for (int i = tid; i < 64 * 128; i += 256) acc[i] = 0.f;
    if (tid < 64) csum[tid] = 0.f;
    int bkt = blockIdx.x;
    int n0 = bkt * 64;
    int lane = tid & 63, wave = tid >> 6;
    __syncthreads();
    int s0 = off[B64 * 8 + bkt * 8] - E_ER;
    int s1 = off[B64 * 8 + (bkt + 1) * 8] - E_ER;
    for (int s = s0 + wave; s < s1; s += 4) {
        uint2 e = gpackM[s];
        int gat = e.x & 0x1FFFF;
        int nl = (e.x >> 17) & 63;
        float w = __uint_as_float(e.y);
        const u16* em = embh + (size_t)gat * 128;
        atomicAdd(&acc[nl * 128 + lane], w * b2f(em[lane]));
        atomicAdd(&acc[nl * 128 + 64 + lane], w * b2f(em[lane + 64]));
        if (lane == 0) atomicAdd(&csum[nl], w);
    }
    __syncthreads();
    for (int i = tid; i < 64 * 64; i += 256) {
        int nl = i >> 6, dp = i & 63;
        int node = n0 + nl;
        if (node < N) {
            float c = csum[nl];
            c = c > 1.f ? c : 1.f;
            float inv = 1.f / c;
            u32 o = (u32)f2b(acc[nl * 128 + 2 * dp] * inv) |
                    ((u32)f2b(acc[nl * 128 + 2 * dp + 1] * inv) << 16);
            *(u32*)(mean_h + (size_t)node * 128 + 2 * dp) = o;
        }
    }
}

// --------- fused epilogue via MFMA: out = sum of 3 tanh(GEMM + bias) ---------
__global__ __launch_bounds__(256) void k_final_mfma(const u16* __restrict__ embh,
                                                    const u16* __restrict__ attn_h,
                                                    const u16* __restrict__ mean_h,
                                                    const u16* __restrict__ W123h,
                                                    const float* __restrict__ b1,
                                                    const float* __restrict__ b2,
                                                    const float* __restrict__ b3,
                                                    float* __restrict__ out, int N) {
    __shared__ u16 sX[3][64][136];
    int nb = blockIdx.x * 64;
    int tid = threadIdx.x;
    const u16* srcs[3] = {embh, attn_h, mean_h};
#pragma unroll
    for (int arr = 0; arr < 3; arr++) {
        const u16* s = srcs[arr];
        for (int i = tid; i < 1024; i += 256) {
            int row = i >> 4, c8 = i & 15;
            int n = nb + row;
            uint4 v = make_uint4(0u, 0u, 0u, 0u);
            if (n < N) v = *(const uint4*)(s + (size_t)n * 128 + c8 * 8);
            *(uint4*)&sX[arr][row][c8 * 8] = v;
        }
    }
    __syncthreads();
    int wid = tid >> 6, lane = tid & 63;
    int quad = lane >> 4, l15 = lane & 15;
#pragma unroll
    for (int ns = 0; ns < 2; ns++) {
        int dbase = (wid * 2 + ns) * 16;
        int d = dbase + l15;
        bf16x8 b[3][4];
#pragma unroll
        for (int arr = 0; arr < 3; arr++)
#pragma unroll
            for (int ks = 0; ks < 4; ks++)
                b[arr][ks] = *(const bf16x8*)(W123h + (size_t)arr * 16384 +
                                              (size_t)d * 128 + ks * 32 + quad * 8);
        float bias0 = b1[d], bias1 = b2[d], bias2 = b3[d];
#pragma unroll
        for (int ms = 0; ms < 4; ms++) {
            f32x4 acc0 = {0.f, 0.f, 0.f, 0.f};
            f32x4 acc1 = {0.f, 0.f, 0.f, 0.f};
            f32x4 acc2 = {0.f, 0.f, 0.f, 0.f};
#pragma unroll
            for (int ks = 0; ks < 4; ks++) {
                bf16x8 a0 = *(const bf16x8*)&sX[0][ms * 16 + l15][ks * 32 + quad * 8];
                bf16x8 a1 = *(const bf16x8*)&sX[1][ms * 16 + l15][ks * 32 + quad * 8];
                bf16x8 a2 = *(const bf16x8*)&sX[2][ms * 16 + l15][ks * 32 + quad * 8];
                acc0 = MFMA16x16(a0, b[0][ks], acc0);
                acc1 = MFMA16x16(a1, b[1][ks], acc1);
                acc2 = MFMA16x16(a2, b[2][ks], acc2);
            }
#pragma unroll
            for (int r = 0; r < 4; r++) {
                int row = nb + ms * 16 + quad * 4 + r;
                if (row < N)
                    out[(size_t)row * 128 + d] = tanh_fast(acc0[r] + bias0) +
                                                 tanh_fast(acc1[r] + bias1) +
                                                 tanh_fast(acc2[r] + bias2);
            }
        }
    }
}

extern "C" void kernel_launch(void* const* d_in, const int* in_sizes, int n_in,
                              void* d_out, int out_size, void* d_ws, size_t ws_size,
                              hipStream_t stream) {
    const float* emb     = (const float*)d_in[0];
    const int*   er_src  = (const int*)d_in[1];
    const int*   er_dst  = (const int*)d_in[2];
    const int*   ee_src  = (const int*)d_in[3];
    const int*   ee_dst  = (const int*)d_in[4];
    const float* ee_w    = (const float*)d_in[5];
    const int*   rr_src  = (const int*)d_in[6];
    const int*   rr_dst  = (const int*)d_in[7];
    const float* Wattn   = (const float*)d_in[8];
    const float* Wattn_b = (const float*)d_in[9];
    const float* w0w     = (const float*)d_in[10];
    const float* w0b     = (const float*)d_in[11];
    const float* W1      = (const float*)d_in[12];
    const float* b1      = (const float*)d_in[13];
    const float* W2      = (const float*)d_in[14];
    const float* b2      = (const float*)d_in[15];
    const float* W3      = (const float*)d_in[16];
    const float* b3      = (const float*)d_in[17];
    float* out = (float*)d_out;

    int N    = in_sizes[0] / D;
    int E_ER = in_sizes[1];
    int E_EE = in_sizes[3];
    int E_RR = in_sizes[6];
    int E_M  = E_ER + E_EE + E_RR;
    int B64  = (N + 63) >> 6;
    int K2   = 2 * B64 * 8;

    char* ws = (char*)d_ws;
    size_t off_b = 0;
    auto alloc = [&](size_t bytes) -> void* {
        void* p = ws + off_b;
        off_b += (bytes + 255) & ~(size_t)255;
        return p;
    };
    // A (N x 256 bf16) dead after k_attn_b; mean_h aliases its first half.
    // Total ws ~= 25.6 + 51.2 + 25.6 + 3.2 + 16 + ~0.5 MB ~= 122 MB.
    u16*   embh   = (u16*)alloc((size_t)N * 128 * 2);
    u16*   A      = (u16*)alloc((size_t)N * 256 * 2);
    u16*   mean_h = A;
    u16*   attn_h = (u16*)alloc((size_t)N * 128 * 2);
    u16*   Wcat_h = (u16*)alloc(256 * 128 * 2);
    u16*   W123h  = (u16*)alloc(3 * 128 * 128 * 2);
    int*   cnt    = (int*)alloc((size_t)K2 * 4);
    int*   off    = (int*)alloc((size_t)(K2 + 1) * 4);
    int*   cur    = (int*)alloc((size_t)K2 * 4);
    u32*   gpackA = (u32*)alloc((size_t)E_ER * 4);
    uint2* gpackM = (uint2*)alloc((size_t)E_M * 8);

    // --- casts (independent) ---
    k_cast4<<<((N * 128 / 4) + 255) / 256, 256, 0, stream>>>(emb, embh, N * 128 / 4);
    k_cast_w<<<(81920 + 255) / 256, 256, 0, stream>>>(Wattn, W1, W2, W3, Wcat_h, W123h);

    // --- bucket build ---
    k_zero<<<(K2 + 255) / 256, 256, 0, stream>>>(cnt, K2);
    k_hist_b<<<64, 256, (size_t)2 * B64 * 4, stream>>>(er_src, er_dst, ee_src, rr_src,
                                                       cnt, E_ER, E_EE, E_RR, B64);
    k_scan_b<<<1, 256, 0, stream>>>(cnt, K2, off, cur);
    k_fill_b<<<512, 256, 0, stream>>>(er_src, er_dst, ee_src, ee_dst, rr_src, rr_dst,
                                      ee_w, cur, gpackA, gpackM, E_ER, E_EE, E_RR, B64);

    // --- compute ---
    k_precompute_mfma<<<(N + 63) / 64, 256, 0, stream>>>(embh, Wcat_h, A, N);
    k_attn_b<<<B64, 256, 0, stream>>>(A, gpackA, off, embh, Wattn_b, w0w, w0b, attn_h, N);
    // A dead; its space becomes mean_h
    k_mean_b<<<B64, 256, 0, stream>>>(gpackM, off, embh, mean_h, N, B64, E_ER);
    k_final_mfma<<<(N + 63) / 64, 256, 0, stream>>>(embh, attn_h, mean_h, W123h,
                                                    b1, b2, b3, out, N);
}